// Round 1
// baseline (436.811 us; speedup 1.0000x reference)
//
#include <hip/hip_runtime.h>
#include <hip/hip_bf16.h>

// MHCLayerAITER: x[B,4,2048] fp32 -> out[B,4,2048] fp32
// out[b,i,c] = sum_j M[i,j]*x[b,j,c] + 2*sig(H_post[i]) * y_norm[b,c]
// y_norm[b,c] = bf16(sum_j sig(H_pre[j])*x[b,j,c]) / rms_b * bf16(w[c])
// M = sinkhorn3(exp(H_res))  (4x4, tiny)
//
// Memory-bound: read x once, write out once. One block per b; x row held in
// registers across the rms reduction so nothing is re-read.

namespace {

constexpr int N = 4;
constexpr int C = 2048;
constexpr int BLOCK = 256;
constexpr int CPT = C / BLOCK;   // 8 c-values per thread
constexpr int VEC = CPT / 4;     // 2 float4 chunks per n-row
constexpr float EPSF = 1e-6f;

__device__ __forceinline__ float bf16r(float v) {
    return __bfloat162float(__float2bfloat16(v));
}

__global__ __launch_bounds__(BLOCK) void mhc_kernel(
    const float* __restrict__ x,       // [B,N,C]
    const float* __restrict__ w,       // [C]
    const float* __restrict__ H_pre,   // [N]
    const float* __restrict__ H_post,  // [N]
    const float* __restrict__ H_res,   // [N,N]
    float* __restrict__ out)           // [B,N,C]
{
    const int b = blockIdx.x;
    const int t = threadIdx.x;

    __shared__ float s_pre[N];
    __shared__ float s_post[N];
    __shared__ float s_P[N][N];
    __shared__ float s_red[BLOCK / 64];
    __shared__ float s_rinv;

    // ---- tiny constants: one thread, hidden under the global loads ----
    if (t == 0) {
        float P[N][N];
        #pragma unroll
        for (int j = 0; j < N; ++j) {
            s_pre[j]  = 1.0f / (1.0f + expf(-H_pre[j]));
            s_post[j] = 2.0f / (1.0f + expf(-H_post[j]));
        }
        #pragma unroll
        for (int i = 0; i < N; ++i)
            #pragma unroll
            for (int j = 0; j < N; ++j)
                P[i][j] = expf(H_res[i * N + j]);
        #pragma unroll
        for (int it = 0; it < 3; ++it) {
            #pragma unroll
            for (int i = 0; i < N; ++i) {
                float rs = P[i][0] + P[i][1] + P[i][2] + P[i][3] + EPSF;
                #pragma unroll
                for (int j = 0; j < N; ++j) P[i][j] = P[i][j] / rs;
            }
            #pragma unroll
            for (int j = 0; j < N; ++j) {
                float cs = P[0][j] + P[1][j] + P[2][j] + P[3][j] + EPSF;
                #pragma unroll
                for (int i = 0; i < N; ++i) P[i][j] = P[i][j] / cs;
            }
        }
        #pragma unroll
        for (int i = 0; i < N; ++i)
            #pragma unroll
            for (int j = 0; j < N; ++j)
                s_P[i][j] = P[i][j];
    }

    // ---- load this b-row of x (4 streams x 8 c) + weight, coalesced float4 ----
    const size_t base = (size_t)b * N * C;
    float xs[N][CPT];
    float ws[CPT];
    #pragma unroll
    for (int j = 0; j < N; ++j) {
        #pragma unroll
        for (int v = 0; v < VEC; ++v) {
            const float4 tmp =
                *(const float4*)(x + base + (size_t)j * C + (size_t)(v * BLOCK + t) * 4);
            xs[j][v * 4 + 0] = tmp.x;
            xs[j][v * 4 + 1] = tmp.y;
            xs[j][v * 4 + 2] = tmp.z;
            xs[j][v * 4 + 3] = tmp.w;
        }
    }
    #pragma unroll
    for (int v = 0; v < VEC; ++v) {
        const float4 tmp = *(const float4*)(w + (size_t)(v * BLOCK + t) * 4);
        ws[v * 4 + 0] = bf16r(tmp.x);
        ws[v * 4 + 1] = bf16r(tmp.y);
        ws[v * 4 + 2] = bf16r(tmp.z);
        ws[v * 4 + 3] = bf16r(tmp.w);
    }

    __syncthreads();   // constants ready

    const float p0 = s_pre[0], p1 = s_pre[1], p2 = s_pre[2], p3 = s_pre[3];

    // ---- sigmoid-weighted aggregate, bf16 round, sum of squares ----
    float agg[CPT];
    float ss = 0.0f;
    #pragma unroll
    for (int k = 0; k < CPT; ++k) {
        float a = p0 * xs[0][k] + p1 * xs[1][k] + p2 * xs[2][k] + p3 * xs[3][k];
        a = bf16r(a);
        agg[k] = a;
        ss += a * a;
    }

    // ---- block reduction over C for rms ----
    #pragma unroll
    for (int off = 32; off > 0; off >>= 1) ss += __shfl_down(ss, off, 64);
    if ((t & 63) == 0) s_red[t >> 6] = ss;
    __syncthreads();
    if (t == 0) {
        float tot = 0.0f;
        #pragma unroll
        for (int i = 0; i < BLOCK / 64; ++i) tot += s_red[i];
        s_rinv = 1.0f / sqrtf(tot / (float)C + EPSF);
    }
    __syncthreads();
    const float rinv = s_rinv;

    // ---- mix streams + combine, write all 4 output rows ----
    float M[N][N], post[N];
    #pragma unroll
    for (int i = 0; i < N; ++i) {
        post[i] = s_post[i];
        #pragma unroll
        for (int j = 0; j < N; ++j) M[i][j] = s_P[i][j];
    }

    #pragma unroll
    for (int i = 0; i < N; ++i) {
        #pragma unroll
        for (int v = 0; v < VEC; ++v) {
            float o[4];
            #pragma unroll
            for (int k = 0; k < 4; ++k) {
                const int idx = v * 4 + k;
                const float yn = agg[idx] * rinv * ws[idx];
                o[k] = M[i][0] * xs[0][idx] + M[i][1] * xs[1][idx]
                     + M[i][2] * xs[2][idx] + M[i][3] * xs[3][idx]
                     + post[i] * yn;
            }
            *(float4*)(out + base + (size_t)i * C + (size_t)(v * BLOCK + t) * 4) =
                *(const float4*)o;
        }
    }
}

}  // namespace

extern "C" void kernel_launch(void* const* d_in, const int* in_sizes, int n_in,
                              void* d_out, int out_size, void* d_ws, size_t ws_size,
                              hipStream_t stream) {
    const float* x      = (const float*)d_in[0];
    const float* w      = (const float*)d_in[1];
    const float* H_pre  = (const float*)d_in[2];
    const float* H_post = (const float*)d_in[3];
    const float* H_res  = (const float*)d_in[4];
    float* out = (float*)d_out;

    const int B = in_sizes[0] / (N * C);   // 8192
    mhc_kernel<<<dim3(B), dim3(BLOCK), 0, stream>>>(x, w, H_pre, H_post, H_res, out);
}

// Round 2
// 424.178 us; speedup vs baseline: 1.0298x; 1.0298x over previous
//
#include <hip/hip_runtime.h>
#include <hip/hip_bf16.h>

// MHCLayerAITER: x[B,4,2048] fp32 -> out[B,4,2048] fp32
// out[b,i,c] = sum_j M[i,j]*x[b,j,c] + 2*sig(H_post[i]) * y_norm[b,c]
// y_norm[b,c] = bf16(sum_j sig(H_pre[j])*x[b,j,c]) / rms_b * bf16(w[c])
// M = sinkhorn3(exp(H_res))  (4x4, tiny -> precomputed once into d_ws)
//
// Memory-bound streaming kernel: read x once (nt), write out once (nt).
// One block per b; x row held in registers across the single-barrier rms
// reduction so nothing is re-read.

namespace {

constexpr int N = 4;
constexpr int C = 2048;
constexpr int BLOCK = 256;
constexpr int CPT = C / BLOCK;   // 8 c-values per thread
constexpr int VEC = CPT / 4;     // 2 float4 chunks per n-row
constexpr float EPSF = 1e-6f;

typedef float f4 __attribute__((ext_vector_type(4)));

__device__ __forceinline__ float bf16r(float v) {
    return __bfloat162float(__float2bfloat16(v));
}

// ---- tiny setup: sigmoids + sinkhorn(exp(H_res)) -> cst[24] in d_ws ----
// cst[0..3]  = sigmoid(H_pre)
// cst[4..7]  = 2*sigmoid(H_post)
// cst[8..23] = M row-major
__global__ void setup_kernel(const float* __restrict__ H_pre,
                             const float* __restrict__ H_post,
                             const float* __restrict__ H_res,
                             float* __restrict__ cst) {
    if (threadIdx.x != 0 || blockIdx.x != 0) return;
    float P[N][N];
    #pragma unroll
    for (int j = 0; j < N; ++j) {
        cst[j]     = 1.0f / (1.0f + expf(-H_pre[j]));
        cst[N + j] = 2.0f / (1.0f + expf(-H_post[j]));
    }
    #pragma unroll
    for (int i = 0; i < N; ++i)
        #pragma unroll
        for (int j = 0; j < N; ++j)
            P[i][j] = expf(H_res[i * N + j]);
    #pragma unroll
    for (int it = 0; it < 3; ++it) {
        #pragma unroll
        for (int i = 0; i < N; ++i) {
            float rs = P[i][0] + P[i][1] + P[i][2] + P[i][3] + EPSF;
            #pragma unroll
            for (int j = 0; j < N; ++j) P[i][j] /= rs;
        }
        #pragma unroll
        for (int j = 0; j < N; ++j) {
            float cs = P[0][j] + P[1][j] + P[2][j] + P[3][j] + EPSF;
            #pragma unroll
            for (int i = 0; i < N; ++i) P[i][j] /= cs;
        }
    }
    #pragma unroll
    for (int i = 0; i < N; ++i)
        #pragma unroll
        for (int j = 0; j < N; ++j)
            cst[2 * N + i * N + j] = P[i][j];
}

__global__ __launch_bounds__(BLOCK) void mhc_kernel(
    const float* __restrict__ x,     // [B,N,C]
    const float* __restrict__ w,     // [C]
    const float* __restrict__ cst,   // [24] precomputed constants
    float* __restrict__ out)         // [B,N,C]
{
    const int b = blockIdx.x;
    const int t = threadIdx.x;

    __shared__ float s_red[BLOCK / 64];

    // wave-uniform constant loads -> SGPRs (no per-block recompute)
    float pre[N], post[N], M[N][N];
    #pragma unroll
    for (int j = 0; j < N; ++j) {
        pre[j]  = cst[j];
        post[j] = cst[N + j];
    }
    #pragma unroll
    for (int i = 0; i < N; ++i)
        #pragma unroll
        for (int j = 0; j < N; ++j)
            M[i][j] = cst[2 * N + i * N + j];

    // ---- load this b-row of x (4 streams x 8 c), nt float4, coalesced ----
    const size_t base = (size_t)b * N * C;
    float xs[N][CPT];
    #pragma unroll
    for (int j = 0; j < N; ++j) {
        #pragma unroll
        for (int v = 0; v < VEC; ++v) {
            const f4 tmp = __builtin_nontemporal_load(
                (const f4*)(x + base + (size_t)j * C + (size_t)(v * BLOCK + t) * 4));
            #pragma unroll
            for (int k = 0; k < 4; ++k) xs[j][v * 4 + k] = tmp[k];
        }
    }
    // weight is reused by all blocks -> cached loads
    float ws[CPT];
    #pragma unroll
    for (int v = 0; v < VEC; ++v) {
        const f4 tmp = *(const f4*)(w + (size_t)(v * BLOCK + t) * 4);
        #pragma unroll
        for (int k = 0; k < 4; ++k) ws[v * 4 + k] = bf16r(tmp[k]);
    }

    // ---- sigmoid-weighted aggregate, bf16 round, sum of squares ----
    float agg[CPT];
    float ss = 0.0f;
    #pragma unroll
    for (int k = 0; k < CPT; ++k) {
        float a = pre[0] * xs[0][k] + pre[1] * xs[1][k]
                + pre[2] * xs[2][k] + pre[3] * xs[3][k];
        a = bf16r(a);
        agg[k] = a;
        ss += a * a;
    }

    // ---- single-barrier block reduction over C for rms ----
    #pragma unroll
    for (int off = 32; off > 0; off >>= 1) ss += __shfl_xor(ss, off, 64);
    if ((t & 63) == 0) s_red[t >> 6] = ss;
    __syncthreads();
    float tot = 0.0f;
    #pragma unroll
    for (int i = 0; i < BLOCK / 64; ++i) tot += s_red[i];
    const float rinv = 1.0f / sqrtf(tot * (1.0f / (float)C) + EPSF);

    // ---- mix streams + combine, write all 4 output rows (nt stores) ----
    #pragma unroll
    for (int i = 0; i < N; ++i) {
        #pragma unroll
        for (int v = 0; v < VEC; ++v) {
            f4 o;
            #pragma unroll
            for (int k = 0; k < 4; ++k) {
                const int idx = v * 4 + k;
                const float yn = agg[idx] * rinv * ws[idx];
                o[k] = M[i][0] * xs[0][idx] + M[i][1] * xs[1][idx]
                     + M[i][2] * xs[2][idx] + M[i][3] * xs[3][idx]
                     + post[i] * yn;
            }
            __builtin_nontemporal_store(
                o, (f4*)(out + base + (size_t)i * C + (size_t)(v * BLOCK + t) * 4));
        }
    }
}

}  // namespace

extern "C" void kernel_launch(void* const* d_in, const int* in_sizes, int n_in,
                              void* d_out, int out_size, void* d_ws, size_t ws_size,
                              hipStream_t stream) {
    const float* x      = (const float*)d_in[0];
    const float* w      = (const float*)d_in[1];
    const float* H_pre  = (const float*)d_in[2];
    const float* H_post = (const float*)d_in[3];
    const float* H_res  = (const float*)d_in[4];
    float* out = (float*)d_out;
    float* cst = (float*)d_ws;   // 24 floats

    const int B = in_sizes[0] / (N * C);   // 8192

    setup_kernel<<<dim3(1), dim3(1), 0, stream>>>(H_pre, H_post, H_res, cst);
    mhc_kernel<<<dim3(B), dim3(BLOCK), 0, stream>>>(x, w, cst, out);
}